// Round 1
// baseline (952.422 us; speedup 1.0000x reference)
//
#include <hip/hip_runtime.h>

// ROI head: pool -> x@W1 relu -> @W2 relu -> @[W_loc|W_score]
// Strategy: everything is HBM-bound on fp32 weight streaming (~480MB).
// bf16 MFMA (truncated weights) so compute never becomes the wall.
// No LDS, no barriers in the GEMM: B streamed global->regs, A via L1.

typedef short short8 __attribute__((ext_vector_type(8)));
typedef float f32x4 __attribute__((ext_vector_type(4)));

__device__ __forceinline__ unsigned short bf16_rne(float f) {
    unsigned int u = __builtin_bit_cast(unsigned int, f);
    unsigned int r = (u + 0x7FFFu + ((u >> 16) & 1u)) >> 16;
    return (unsigned short)r;
}

// ---------------- pooling: [512,38,50] -> x bf16 [128][25088] ----------------
__global__ void pool_kernel(const float* __restrict__ F,     // [512][38][50]
                            const float* __restrict__ rois,  // [128][4] y1,x1,y2,x2
                            unsigned short* __restrict__ X)  // [128][25088]
{
    const int r = blockIdx.x;
    const float4 rv = ((const float4*)rois)[r];
    const int y0 = (int)truncf(rv.x * 0.0625f);
    const int x0 = (int)truncf(rv.y * 0.0625f);
    const int y2 = (int)ceilf (rv.z * 0.0625f);
    const int x3 = (int)ceilf (rv.w * 0.0625f);
    const int Ly = y2 - y0, Lx = x3 - x0;

    for (int out = threadIdx.x; out < 25088; out += 256) {
        int c = out / 49, rem = out % 49;
        int i = rem / 7, j = rem % 7;
        // adaptive-pool bins (ints >= 0, C '/' == floor)
        int rb0 = y0 + (i * Ly) / 7;
        int re  = y0 + ((i + 1) * Ly + 6) / 7;
        re = min(re, rb0 + 7);   // Kr cap (matches reference mask width)
        re = min(re, 38);
        int cb0 = x0 + (j * Lx) / 7;
        int ce  = x0 + ((j + 1) * Lx + 6) / 7;
        ce = min(ce, cb0 + 9);   // Kc cap
        ce = min(ce, 50);
        float m = -3.4e38f;
        const float* fc = F + c * 1900;
        for (int rr = rb0; rr < re; ++rr)
            for (int cc = cb0; cc < ce; ++cc)
                m = fmaxf(m, fc[rr * 50 + cc]);
        X[r * 25088 + out] = bf16_rne(m);
    }
}

// ---------------- GEMM: C_partial[sp] = A[128xK_chunk] * B[K][4096] ----------
// block = 4 waves; wave w owns cols [bx*64+16w, +16), all 128 rows (8 MFMA tiles)
template <int LDA>
__global__ __launch_bounds__(256, 2)
void gemm_kernel(const unsigned short* __restrict__ A,  // bf16 bits [128][LDA]
                 const float* __restrict__ B,           // [K][4096] fp32
                 float* __restrict__ P,                 // [S][128][4096] fp32
                 int Kchunk)
{
    constexpr int N = 4096;
    const int lane = threadIdx.x & 63;
    const int w    = threadIdx.x >> 6;
    const int q    = lane >> 4;            // k-quad
    const int col  = blockIdx.x * 64 + w * 16 + (lane & 15);
    const int sp   = blockIdx.y;
    const int kbeg = sp * Kchunk;

    f32x4 acc[8] = {};
    const unsigned short* a_base = A + (lane & 15) * LDA + kbeg + q * 8;
    const float*          b_base = B + (size_t)(kbeg + q * 8) * N + col;

    for (int ks = 0; ks < Kchunk; ks += 32) {
        short8 afrag[8];
#pragma unroll
        for (int t = 0; t < 8; ++t)
            afrag[t] = *(const short8*)(a_base + (size_t)t * 16 * LDA);
        float bv[8];
#pragma unroll
        for (int j = 0; j < 8; ++j)
            bv[j] = b_base[(size_t)j * N];
        short8 bfrag;
#pragma unroll
        for (int j = 0; j < 8; ++j) {
            unsigned int u = __builtin_bit_cast(unsigned int, bv[j]);
            bfrag[j] = (short)(u >> 16);   // truncate fp32->bf16
        }
#pragma unroll
        for (int t = 0; t < 8; ++t)
            acc[t] = __builtin_amdgcn_mfma_f32_16x16x32_bf16(afrag[t], bfrag, acc[t], 0, 0, 0);
        a_base += 32;
        b_base += (size_t)32 * N;
    }

    float* p = P + (size_t)sp * 128 * N + col;
#pragma unroll
    for (int t = 0; t < 8; ++t)
#pragma unroll
        for (int r = 0; r < 4; ++r)
            p[(size_t)(16 * t + q * 4 + r) * N] = acc[t][r];
}

// ---------------- head GEMM: cols 0..83 -> W_loc, 84..104 -> W_score ---------
__global__ __launch_bounds__(256, 2)
void gemm_head_kernel(const unsigned short* __restrict__ A,  // h2 bf16 [128][4096]
                      const float* __restrict__ Wl,          // [4096][84]
                      const float* __restrict__ Ws,          // [4096][21]
                      float* __restrict__ P,                 // [S][128][112]
                      int Kchunk)
{
    constexpr int LDA = 4096;
    const int lane = threadIdx.x & 63;
    const int w    = threadIdx.x >> 6;
    const int q    = lane >> 4;
    const int col  = blockIdx.x * 64 + w * 16 + (lane & 15);  // 0..127
    const int sp   = blockIdx.y;
    const int kbeg = sp * Kchunk;

    int stride; const float* bp;
    if (col < 84)       { stride = 84; bp = Wl + col; }
    else if (col < 105) { stride = 21; bp = Ws + (col - 84); }
    else                { stride = 0;  bp = Ws; }              // inert lanes
    bp += (size_t)(kbeg + q * 8) * stride;

    f32x4 acc[8] = {};
    const unsigned short* a_base = A + (lane & 15) * LDA + kbeg + q * 8;

    for (int ks = 0; ks < Kchunk; ks += 32) {
        short8 afrag[8];
#pragma unroll
        for (int t = 0; t < 8; ++t)
            afrag[t] = *(const short8*)(a_base + (size_t)t * 16 * LDA);
        short8 bfrag;
#pragma unroll
        for (int j = 0; j < 8; ++j) {
            unsigned int u = __builtin_bit_cast(unsigned int, bp[(size_t)j * stride]);
            bfrag[j] = (short)(u >> 16);
        }
#pragma unroll
        for (int t = 0; t < 8; ++t)
            acc[t] = __builtin_amdgcn_mfma_f32_16x16x32_bf16(afrag[t], bfrag, acc[t], 0, 0, 0);
        a_base += 32;
        bp += (size_t)32 * stride;
    }

    if (col < 112) {
        float* p = P + (size_t)sp * 128 * 112 + col;
#pragma unroll
        for (int t = 0; t < 8; ++t)
#pragma unroll
            for (int r = 0; r < 4; ++r)
                p[(size_t)(16 * t + q * 4 + r) * 112] = acc[t][r];
    }
}

// ---------------- split-K reduce + bias + relu -> bf16 -----------------------
__global__ void reduce_relu_kernel(const float* __restrict__ P,     // [8][128][4096]
                                   const float* __restrict__ bias,  // [4096]
                                   unsigned short* __restrict__ H)  // bf16 [128][4096]
{
    const int e = blockIdx.x * 256 + threadIdx.x;
    if (e >= 128 * 4096) return;
    constexpr int NT = 128 * 4096;
    float s = 0.f;
#pragma unroll
    for (int i = 0; i < 8; ++i) s += P[(size_t)i * NT + e];
    s += bias[e & 4095];
    s = fmaxf(s, 0.f);
    H[e] = bf16_rne(s);
}

// ---------------- head reduce + bias -> d_out (locs then scores) -------------
__global__ void reduce_head_kernel(const float* __restrict__ P,   // [32][128][112]
                                   const float* __restrict__ bl,  // [84]
                                   const float* __restrict__ bs,  // [21]
                                   float* __restrict__ out)       // 128*84 + 128*21
{
    const int e = blockIdx.x * 256 + threadIdx.x;
    if (e >= 128 * 112) return;
    const int m = e / 112, col = e % 112;
    if (col >= 105) return;
    float s = 0.f;
#pragma unroll
    for (int i = 0; i < 32; ++i) s += P[(size_t)i * 128 * 112 + e];
    if (col < 84) out[m * 84 + col] = s + bl[col];
    else          out[128 * 84 + m * 21 + (col - 84)] = s + bs[col - 84];
}

extern "C" void kernel_launch(void* const* d_in, const int* in_sizes, int n_in,
                              void* d_out, int out_size, void* d_ws, size_t ws_size,
                              hipStream_t stream)
{
    const float* feats = (const float*)d_in[0];
    const float* rois  = (const float*)d_in[1];
    const float* W1    = (const float*)d_in[2];
    const float* b1    = (const float*)d_in[3];
    const float* W2    = (const float*)d_in[4];
    const float* b2    = (const float*)d_in[5];
    const float* Wl    = (const float*)d_in[6];
    const float* bl    = (const float*)d_in[7];
    const float* Wsc   = (const float*)d_in[8];
    const float* bsc   = (const float*)d_in[9];
    float* out = (float*)d_out;

    char* ws = (char*)d_ws;
    unsigned short* X  = (unsigned short*)(ws);             // 128*25088*2 = 6,422,528
    unsigned short* H1 = (unsigned short*)(ws + 6422528);   // 1,048,576
    unsigned short* H2 = (unsigned short*)(ws + 7471104);   // 1,048,576
    float* P           = (float*)(ws + 8519680);            // 16 MB partials (reused)

    pool_kernel<<<128, 256, 0, stream>>>(feats, rois, X);

    // GEMM1: K=25088, split 8 -> Kchunk 3136 (98 steps), 512 blocks
    gemm_kernel<25088><<<dim3(64, 8), 256, 0, stream>>>(X, W1, P, 3136);
    reduce_relu_kernel<<<2048, 256, 0, stream>>>(P, b1, H1);

    // GEMM2: K=4096, split 8 -> Kchunk 512
    gemm_kernel<4096><<<dim3(64, 8), 256, 0, stream>>>(H1, W2, P, 512);
    reduce_relu_kernel<<<2048, 256, 0, stream>>>(P, b2, H2);

    // head: K=4096, split 32 -> Kchunk 128; 2 n-blocks cover 105 (pad 112/128)
    gemm_head_kernel<<<dim3(2, 32), 256, 0, stream>>>(H2, Wl, Wsc, P, 128);
    reduce_head_kernel<<<56, 256, 0, stream>>>(P, bl, bsc, out);
}

// Round 2
// 882.850 us; speedup vs baseline: 1.0788x; 1.0788x over previous
//
#include <hip/hip_runtime.h>

// ROI head: pool -> x@W1 relu -> @W2 relu -> @[W_loc|W_score]
// HBM-bound on fp32 weight streaming (~480MB). bf16 MFMA so compute is never
// the wall. GEMMs: no LDS/barriers, B streamed global->regs with distance-1
// prefetch, split-K 16 for occupancy. Pool: features transposed to [HW][C]
// so lanes (=channels) read coalesced.

typedef short short8 __attribute__((ext_vector_type(8)));
typedef float f32x4 __attribute__((ext_vector_type(4)));

__device__ __forceinline__ unsigned short bf16_rne(float f) {
    unsigned int u = __builtin_bit_cast(unsigned int, f);
    unsigned int r = (u + 0x7FFFu + ((u >> 16) & 1u)) >> 16;
    return (unsigned short)r;
}

// ---------------- transpose F[512][1900] -> FT[1900][512] -------------------
__global__ void transpose_kernel(const float* __restrict__ F,
                                 float* __restrict__ FT)
{
    __shared__ float t[32][33];
    const int xs = blockIdx.x * 32;   // spatial 0..1899
    const int cs = blockIdx.y * 32;   // channel 0..511
    const int tx = threadIdx.x, ty = threadIdx.y;  // 32 x 8
#pragma unroll
    for (int k = 0; k < 4; ++k) {
        int cc = cs + ty + k * 8;
        int xx = xs + tx;
        if (xx < 1900) t[ty + k * 8][tx] = F[cc * 1900 + xx];
    }
    __syncthreads();
#pragma unroll
    for (int k = 0; k < 4; ++k) {
        int xx = xs + ty + k * 8;
        int cc = cs + tx;
        if (xx < 1900) FT[xx * 512 + cc] = t[tx][ty + k * 8];
    }
}

// ---------------- pooling: FT[1900][512] -> X bf16 [128][25088] -------------
__global__ void pool_kernel(const float* __restrict__ FT,
                            const float* __restrict__ rois,
                            unsigned short* __restrict__ X)
{
    __shared__ unsigned short tile[256 * 49];
    const int r = blockIdx.x;
    const int c = blockIdx.y * 256 + threadIdx.x;   // channel
    const float4 rv = ((const float4*)rois)[r];
    const int y0 = (int)truncf(rv.x * 0.0625f);
    const int x0 = (int)truncf(rv.y * 0.0625f);
    const int y2 = (int)ceilf (rv.z * 0.0625f);
    const int x3 = (int)ceilf (rv.w * 0.0625f);
    const int Ly = y2 - y0, Lx = x3 - x0;

    int rb[7], re[7], cb[7], ce[7];
#pragma unroll
    for (int i = 0; i < 7; ++i) {
        rb[i] = y0 + (i * Ly) / 7;
        re[i] = min(min(y0 + ((i + 1) * Ly + 6) / 7, rb[i] + 7), 38);  // Kr=7 cap
        cb[i] = x0 + (i * Lx) / 7;
        ce[i] = min(min(x0 + ((i + 1) * Lx + 6) / 7, cb[i] + 9), 50);  // Kc=9 cap
    }

    int o = 0;
    for (int i = 0; i < 7; ++i) {
        for (int j = 0; j < 7; ++j) {
            float m = -3.4e38f;
            for (int rr = rb[i]; rr < re[i]; ++rr)
                for (int cc = cb[j]; cc < ce[j]; ++cc)
                    m = fmaxf(m, FT[(rr * 50 + cc) * 512 + c]);
            tile[threadIdx.x * 49 + o] = bf16_rne(m);
            ++o;
        }
    }
    __syncthreads();
    // coalesced copy-out: X[r][by*256*49 + t]
    unsigned int* dst = (unsigned int*)(X + r * 25088 + blockIdx.y * (256 * 49));
    const unsigned int* src = (const unsigned int*)tile;
    for (int t = threadIdx.x; t < 256 * 49 / 2; t += 256) dst[t] = src[t];
}

// ---------------- GEMM: P[sp] = A[128 x Kchunk] * B[K][4096] ----------------
// 4 waves/block; wave w owns cols [bx*64+16w,+16), all 128 rows (8 MFMA tiles)
template <int LDA>
__global__ __launch_bounds__(256, 4)
void gemm_kernel(const unsigned short* __restrict__ A,  // bf16 bits [128][LDA]
                 const float* __restrict__ B,           // [K][4096]
                 float* __restrict__ P,                 // [S][128][4096]
                 int Kchunk)
{
    constexpr int N = 4096;
    const int lane = threadIdx.x & 63;
    const int w    = threadIdx.x >> 6;
    const int q    = lane >> 4;
    const int col  = blockIdx.x * 64 + w * 16 + (lane & 15);
    const int sp   = blockIdx.y;
    const int kbeg = sp * Kchunk;

    f32x4 acc[8] = {};
    const unsigned short* a_base = A + (lane & 15) * LDA + kbeg + q * 8;
    const float*          b_base = B + (size_t)(kbeg + q * 8) * N + col;

    float bv[8];
#pragma unroll
    for (int j = 0; j < 8; ++j) bv[j] = b_base[(size_t)j * N];

    for (int ks = 0; ks < Kchunk; ks += 32) {
        float bvn[8];
        if (ks + 32 < Kchunk) {
            const float* bn = b_base + (size_t)32 * N;
#pragma unroll
            for (int j = 0; j < 8; ++j) bvn[j] = bn[(size_t)j * N];
        }
        short8 afrag[8];
#pragma unroll
        for (int t = 0; t < 8; ++t)
            afrag[t] = *(const short8*)(a_base + (size_t)t * 16 * LDA);
        short8 bfrag;
#pragma unroll
        for (int j = 0; j < 8; ++j)
            bfrag[j] = (short)bf16_rne(bv[j]);
#pragma unroll
        for (int t = 0; t < 8; ++t)
            acc[t] = __builtin_amdgcn_mfma_f32_16x16x32_bf16(afrag[t], bfrag, acc[t], 0, 0, 0);
#pragma unroll
        for (int j = 0; j < 8; ++j) bv[j] = bvn[j];
        a_base += 32;
        b_base += (size_t)32 * N;
    }

    float* p = P + (size_t)sp * 128 * N + col;
#pragma unroll
    for (int t = 0; t < 8; ++t)
#pragma unroll
        for (int r = 0; r < 4; ++r)
            p[(size_t)(16 * t + q * 4 + r) * N] = acc[t][r];
}

// ---------------- head GEMM: cols 0..83 -> W_loc, 84..104 -> W_score --------
__global__ __launch_bounds__(256, 4)
void gemm_head_kernel(const unsigned short* __restrict__ A,  // h2 bf16 [128][4096]
                      const float* __restrict__ Wl,          // [4096][84]
                      const float* __restrict__ Ws,          // [4096][21]
                      float* __restrict__ P,                 // [S][128][112]
                      int Kchunk)
{
    constexpr int LDA = 4096;
    const int lane = threadIdx.x & 63;
    const int w    = threadIdx.x >> 6;
    const int q    = lane >> 4;
    const int col  = blockIdx.x * 64 + w * 16 + (lane & 15);  // 0..127
    const int sp   = blockIdx.y;
    const int kbeg = sp * Kchunk;

    int stride; const float* bp;
    if (col < 84)       { stride = 84; bp = Wl + col; }
    else if (col < 105) { stride = 21; bp = Ws + (col - 84); }
    else                { stride = 0;  bp = Ws; }
    bp += (size_t)(kbeg + q * 8) * stride;

    f32x4 acc[8] = {};
    const unsigned short* a_base = A + (lane & 15) * LDA + kbeg + q * 8;

    for (int ks = 0; ks < Kchunk; ks += 32) {
        short8 afrag[8];
#pragma unroll
        for (int t = 0; t < 8; ++t)
            afrag[t] = *(const short8*)(a_base + (size_t)t * 16 * LDA);
        short8 bfrag;
#pragma unroll
        for (int j = 0; j < 8; ++j)
            bfrag[j] = (short)bf16_rne(bp[(size_t)j * stride]);
#pragma unroll
        for (int t = 0; t < 8; ++t)
            acc[t] = __builtin_amdgcn_mfma_f32_16x16x32_bf16(afrag[t], bfrag, acc[t], 0, 0, 0);
        a_base += 32;
        bp += (size_t)32 * stride;
    }

    if (col < 112) {
        float* p = P + (size_t)sp * 128 * 112 + col;
#pragma unroll
        for (int t = 0; t < 8; ++t)
#pragma unroll
            for (int r = 0; r < 4; ++r)
                p[(size_t)(16 * t + q * 4 + r) * 112] = acc[t][r];
    }
}

// ---------------- split-K reduce + bias + relu -> bf16 ----------------------
__global__ void reduce_relu_kernel(const float* __restrict__ P,     // [16][128][4096]
                                   const float* __restrict__ bias,  // [4096]
                                   unsigned short* __restrict__ H)  // bf16 [128][4096]
{
    const int e = blockIdx.x * 256 + threadIdx.x;
    if (e >= 128 * 4096) return;
    constexpr int NT = 128 * 4096;
    float s = 0.f;
#pragma unroll
    for (int i = 0; i < 16; ++i) s += P[(size_t)i * NT + e];
    s += bias[e & 4095];
    s = fmaxf(s, 0.f);
    H[e] = bf16_rne(s);
}

// ---------------- head reduce + bias -> d_out (locs then scores) ------------
__global__ void reduce_head_kernel(const float* __restrict__ P,   // [64][128][112]
                                   const float* __restrict__ bl,  // [84]
                                   const float* __restrict__ bs,  // [21]
                                   float* __restrict__ out)       // 128*84 + 128*21
{
    const int e = blockIdx.x * 256 + threadIdx.x;
    if (e >= 128 * 112) return;
    const int m = e / 112, col = e % 112;
    if (col >= 105) return;
    float s = 0.f;
#pragma unroll
    for (int i = 0; i < 64; ++i) s += P[(size_t)i * 128 * 112 + e];
    if (col < 84) out[m * 84 + col] = s + bl[col];
    else          out[128 * 84 + m * 21 + (col - 84)] = s + bs[col - 84];
}

extern "C" void kernel_launch(void* const* d_in, const int* in_sizes, int n_in,
                              void* d_out, int out_size, void* d_ws, size_t ws_size,
                              hipStream_t stream)
{
    const float* feats = (const float*)d_in[0];
    const float* rois  = (const float*)d_in[1];
    const float* W1    = (const float*)d_in[2];
    const float* b1    = (const float*)d_in[3];
    const float* W2    = (const float*)d_in[4];
    const float* b2    = (const float*)d_in[5];
    const float* Wl    = (const float*)d_in[6];
    const float* bl    = (const float*)d_in[7];
    const float* Wsc   = (const float*)d_in[8];
    const float* bsc   = (const float*)d_in[9];
    float* out = (float*)d_out;

    char* ws = (char*)d_ws;
    unsigned short* X  = (unsigned short*)(ws);              // 6,422,528 B
    unsigned short* H1 = (unsigned short*)(ws + 6422528);    // 1,048,576 B
    unsigned short* H2 = (unsigned short*)(ws + 7471104);    // 1,048,576 B
    float* FT          = (float*)(ws + 8519680);             // 3,891,200 B
    float* P           = (float*)(ws + 12410880);            // 33.5 MB partials

    transpose_kernel<<<dim3(60, 16), dim3(32, 8), 0, stream>>>(feats, FT);
    pool_kernel<<<dim3(128, 2), 256, 0, stream>>>(FT, rois, X);

    // GEMM1: K=25088, split 16 -> Kchunk 1568 (49 steps), 1024 blocks
    gemm_kernel<25088><<<dim3(64, 16), 256, 0, stream>>>(X, W1, P, 1568);
    reduce_relu_kernel<<<2048, 256, 0, stream>>>(P, b1, H1);

    // GEMM2: K=4096, split 16 -> Kchunk 256
    gemm_kernel<4096><<<dim3(64, 16), 256, 0, stream>>>(H1, W2, P, 256);
    reduce_relu_kernel<<<2048, 256, 0, stream>>>(P, b2, H2);

    // head: K=4096, split 64 -> Kchunk 64; 2 n-blocks cover 105 (pad 112/128)
    gemm_head_kernel<<<dim3(2, 64), 256, 0, stream>>>(H2, Wl, Wsc, P, 64);
    reduce_head_kernel<<<56, 256, 0, stream>>>(P, bl, bsc, out);
}